// Round 1
// baseline (901.415 us; speedup 1.0000x reference)
//
#include <hip/hip_runtime.h>
#include <cstddef>

// Problem constants (static per reference)
#define B_ 2
#define Q_ 300
#define T_ 25
#define C_ 256
#define NH_ 8
#define NL_ 4
#define NP_ 4
#define HD_ 32
#define DFF_ 1024
#define LQ_ (Q_ * T_)           // 7500
#define NTOK_ (B_ * LQ_)        // 15000
#define S_ 21760                // sum of level sizes
#define BS_ (B_ * S_)           // 43520

// ---------------- generic fp32 GEMM: C[M,N] = act(A[M,K] @ W[N,K]^T + bias[N]) ----------------
#define BM 64
#define BN 64
#define BK 16

__global__ __launch_bounds__(256) void gemm_bias(
    const float* __restrict__ A, const float* __restrict__ W,
    const float* __restrict__ bias, float* __restrict__ C,
    int M, int N, int K, int ldc, int relu)
{
    __shared__ float As[BK][BM + 4];
    __shared__ float Ws[BK][BN + 4];
    int m0 = blockIdx.x * BM;
    int n0 = blockIdx.y * BN;
    int t = threadIdx.x;
    int tm = t >> 4, tn = t & 15;     // 16x16 thread grid, 4x4 microtile
    int lr = t >> 2;                  // 0..63 tile row for loads
    int lk = (t & 3) * 4;             // k offset 0,4,8,12

    float acc[4][4] = {};

    for (int k0 = 0; k0 < K; k0 += BK) {
        float4 av;
        int gm = m0 + lr;
        if (gm < M) av = *(const float4*)(A + (size_t)gm * K + k0 + lk);
        else av = make_float4(0.f, 0.f, 0.f, 0.f);
        As[lk + 0][lr] = av.x; As[lk + 1][lr] = av.y;
        As[lk + 2][lr] = av.z; As[lk + 3][lr] = av.w;

        float4 wv = *(const float4*)(W + (size_t)(n0 + lr) * K + k0 + lk);
        Ws[lk + 0][lr] = wv.x; Ws[lk + 1][lr] = wv.y;
        Ws[lk + 2][lr] = wv.z; Ws[lk + 3][lr] = wv.w;
        __syncthreads();

        #pragma unroll
        for (int kk = 0; kk < BK; ++kk) {
            float a[4], b[4];
            #pragma unroll
            for (int i = 0; i < 4; ++i) a[i] = As[kk][tm * 4 + i];
            #pragma unroll
            for (int j = 0; j < 4; ++j) b[j] = Ws[kk][tn * 4 + j];
            #pragma unroll
            for (int i = 0; i < 4; ++i)
                #pragma unroll
                for (int j = 0; j < 4; ++j)
                    acc[i][j] += a[i] * b[j];
        }
        __syncthreads();
    }

    #pragma unroll
    for (int i = 0; i < 4; ++i) {
        int m = m0 + tm * 4 + i;
        if (m >= M) continue;
        #pragma unroll
        for (int j = 0; j < 4; ++j) {
            int n = n0 + tn * 4 + j;
            float v = acc[i][j] + bias[n];
            if (relu) v = fmaxf(v, 0.f);
            C[(size_t)m * ldc + n] = v;
        }
    }
}

// ---------------- elementwise add ----------------
__global__ __launch_bounds__(256) void add_kernel(
    const float* __restrict__ a, const float* __restrict__ b,
    float* __restrict__ o, int n)
{
    int i = blockIdx.x * 256 + threadIdx.x;
    if (i < n) o[i] = a[i] + b[i];
}

// ---------------- self-attention over T=25, one wave per (seq, head) ----------------
__global__ __launch_bounds__(64) void attn_kernel(
    const float* __restrict__ qkv,   // [NTOK, 768]: q|k|v per token
    float* __restrict__ o)           // [NTOK, 256]
{
    int sh = blockIdx.x;
    int s = sh >> 3, h = sh & 7;     // s in [0, 600), h in [0, 8)
    __shared__ float qs[T_][HD_], ks[T_][HD_], vs[T_][HD_];
    int t = threadIdx.x;

    for (int idx = t; idx < T_ * HD_; idx += 64) {
        int i = idx >> 5, d = idx & 31;
        size_t base = ((size_t)(s * T_ + i)) * 768 + h * HD_ + d;
        qs[i][d] = qkv[base];
        ks[i][d] = qkv[base + 256];
        vs[i][d] = qkv[base + 512];
    }
    __syncthreads();

    if (t < T_) {
        float sc[T_];
        float mx = -1e30f;
        #pragma unroll
        for (int j = 0; j < T_; ++j) {
            float dot = 0.f;
            #pragma unroll
            for (int d = 0; d < HD_; ++d) dot += qs[t][d] * ks[j][d];
            sc[j] = dot * 0.17677669529663687f;  // 1/sqrt(32)
            mx = fmaxf(mx, sc[j]);
        }
        float sum = 0.f;
        #pragma unroll
        for (int j = 0; j < T_; ++j) { sc[j] = __expf(sc[j] - mx); sum += sc[j]; }
        float inv = 1.f / sum;
        float out[HD_];
        #pragma unroll
        for (int d = 0; d < HD_; ++d) out[d] = 0.f;
        for (int j = 0; j < T_; ++j) {
            float p = sc[j] * inv;
            #pragma unroll
            for (int d = 0; d < HD_; ++d) out[d] += p * vs[j][d];
        }
        size_t ob = ((size_t)(s * T_ + t)) * C_ + h * HD_;
        #pragma unroll
        for (int d = 0; d < HD_; ++d) o[ob + d] = out[d];
    }
}

// ---------------- fused residual + LayerNorm (+ optional query = out + pos) ----------------
__global__ __launch_bounds__(256) void ln_kernel(
    const float* __restrict__ x, const float* __restrict__ r,
    const float* __restrict__ g, const float* __restrict__ b,
    float* __restrict__ out, const float* __restrict__ pos,
    float* __restrict__ qout)
{
    int tok = blockIdx.x;
    int t = threadIdx.x;
    size_t base = (size_t)tok * C_;
    float v = x[base + t] + r[base + t];

    float s = v, ss = v * v;
    #pragma unroll
    for (int off = 32; off; off >>= 1) {
        s += __shfl_down(s, off);
        ss += __shfl_down(ss, off);
    }
    __shared__ float ws[4], wss[4];
    __shared__ float mean_s, rstd_s;
    int wid = t >> 6, lane = t & 63;
    if (lane == 0) { ws[wid] = s; wss[wid] = ss; }
    __syncthreads();
    if (t == 0) {
        float S = 0.f, SS = 0.f;
        #pragma unroll
        for (int i = 0; i < 4; ++i) { S += ws[i]; SS += wss[i]; }
        float m = S / 256.f;
        float var = SS / 256.f - m * m;
        mean_s = m;
        rstd_s = rsqrtf(var + 1e-5f);
    }
    __syncthreads();
    float y = (v - mean_s) * rstd_s * g[t] + b[t];
    out[base + t] = y;
    if (qout) qout[base + t] = y + pos[base + t];
}

// ---------------- deformable sampling, 32 lanes per (token, head), aw-softmax fused ----------------
__global__ __launch_bounds__(256) void deform_kernel(
    const float* __restrict__ value,      // [B, S, NH, HD]
    const float* __restrict__ off,        // [NTOK, 256]
    const float* __restrict__ aw_logits,  // [NTOK, 128]
    const float* __restrict__ refpts,     // [B, LQ, NL, 2]
    float* __restrict__ out)              // [NTOK, 256] laid out (tok, h, d)
{
    int unit = blockIdx.x * 8 + (threadIdx.x >> 5);  // (tok, h)
    int d = threadIdx.x & 31;
    int h = unit & 7;
    int tok = unit >> 3;                 // b*LQ + lq
    int b = tok / LQ_;

    // softmax over 16 attention-weight logits (redundant per lane; broadcast loads)
    const float* awp = aw_logits + (size_t)tok * 128 + h * 16;
    float logit[16];
    float mx = -1e30f;
    #pragma unroll
    for (int i = 0; i < 16; ++i) { logit[i] = awp[i]; mx = fmaxf(mx, logit[i]); }
    float sum = 0.f;
    #pragma unroll
    for (int i = 0; i < 16; ++i) { logit[i] = __expf(logit[i] - mx); sum += logit[i]; }
    float inv = 1.f / sum;

    const float* offp = off + (size_t)tok * 256 + h * 32;
    const float* refp = refpts + (size_t)tok * (NL_ * 2);

    const int HW[4]     = {128, 64, 32, 16};
    const int starts[4] = {0, 16384, 20480, 21504};

    float acc = 0.f;
    #pragma unroll
    for (int l = 0; l < 4; ++l) {
        const int Hl = HW[l], Wl = HW[l];
        float rx = refp[l * 2 + 0], ry = refp[l * 2 + 1];
        const float* vbase = value + ((size_t)b * S_ + starts[l]) * (NH_ * HD_) + h * HD_ + d;
        #pragma unroll
        for (int p = 0; p < 4; ++p) {
            float ox = offp[(l * 4 + p) * 2 + 0];
            float oy = offp[(l * 4 + p) * 2 + 1];
            float xl = rx * (float)Wl + ox - 0.5f;
            float yl = ry * (float)Hl + oy - 0.5f;
            float x0f = floorf(xl), y0f = floorf(yl);
            int x0 = (int)x0f, y0 = (int)y0f;
            float wx1 = xl - x0f, wy1 = yl - y0f;
            float wx0 = 1.f - wx1, wy0 = 1.f - wy1;
            float aww = logit[l * 4 + p] * inv;

            float sv = 0.f;
            #pragma unroll
            for (int c = 0; c < 4; ++c) {
                int dx = c & 1, dy = c >> 1;
                int xi = x0 + dx, yi = y0 + dy;
                float w = (dx ? wx1 : wx0) * (dy ? wy1 : wy0);
                bool valid = (xi >= 0) & (xi < Wl) & (yi >= 0) & (yi < Hl);
                int xc = min(max(xi, 0), Wl - 1);
                int yc = min(max(yi, 0), Hl - 1);
                float gv = vbase[((size_t)(yc * Wl + xc)) * (NH_ * HD_)];
                sv += gv * (valid ? w : 0.f);
            }
            acc += aww * sv;
        }
    }
    out[(size_t)tok * C_ + h * HD_ + d] = acc;
}

// ---------------- host launch ----------------
extern "C" void kernel_launch(void* const* d_in, const int* in_sizes, int n_in,
                              void* d_out, int out_size, void* d_ws, size_t ws_size,
                              hipStream_t stream) {
    const float* tgt_text = (const float*)d_in[0];
    const float* pos      = (const float*)d_in[1];
    const float* refpts   = (const float*)d_in[2];
    const float* src      = (const float*)d_in[3];
    // d_in[4], d_in[5]: spatial shapes / level starts (static, unused)
    const float* in_proj_w  = (const float*)d_in[6];
    const float* in_proj_b  = (const float*)d_in[7];
    const float* out_proj_w = (const float*)d_in[8];
    const float* out_proj_b = (const float*)d_in[9];
    const float* ln1_g = (const float*)d_in[10];
    const float* ln1_b = (const float*)d_in[11];
    const float* samp_off_w = (const float*)d_in[12];
    const float* samp_off_b = (const float*)d_in[13];
    const float* aw_w = (const float*)d_in[14];
    const float* aw_b = (const float*)d_in[15];
    const float* vp_w = (const float*)d_in[16];
    const float* vp_b = (const float*)d_in[17];
    const float* op_w = (const float*)d_in[18];
    const float* op_b = (const float*)d_in[19];
    const float* ln2_g = (const float*)d_in[20];
    const float* ln2_b = (const float*)d_in[21];
    const float* ffn1_w = (const float*)d_in[22];
    const float* ffn1_b = (const float*)d_in[23];
    const float* ffn2_w = (const float*)d_in[24];
    const float* ffn2_b = (const float*)d_in[25];
    const float* ln3_g = (const float*)d_in[26];
    const float* ln3_b = (const float*)d_in[27];

    const size_t NC = (size_t)NTOK_ * C_;      // 3,840,000
    float* ws = (float*)d_ws;
    float* A    = ws;                 // [NTOK,C]   tgt (post-LN1, post-LN2)
    float* Bq   = ws + NC;            // [NTOK,C]   qk input / query
    float* Creg = ws + 2 * NC;        // 15,360,000 floats: qkv -> value -> ffn hidden
    float* D1   = Creg + (size_t)NTOK_ * DFF_;       // [NTOK,256] sampling offsets
    float* D2   = D1 + NC;                            // [NTOK,128] aw logits
    float* E    = D2 + (size_t)NTOK_ * 128;           // [NTOK,C]   attn out / deform accum
    float* F    = E + NC;                             // [NTOK,C]   tgt2 / cross / ffn2

    const int MB = (NTOK_ + BM - 1) / BM;  // 235

    // 1. qk input = tgt + pos
    add_kernel<<<(int)((NC + 255) / 256), 256, 0, stream>>>(tgt_text, pos, Bq, (int)NC);
    // 2. QK projection (cols 0..511 of qkv), V projection (cols 512..767)
    gemm_bias<<<dim3(MB, 8), 256, 0, stream>>>(Bq, in_proj_w, in_proj_b, Creg,
                                               NTOK_, 512, 256, 768, 0);
    gemm_bias<<<dim3(MB, 4), 256, 0, stream>>>(tgt_text, in_proj_w + 512 * 256, in_proj_b + 512,
                                               Creg + 512, NTOK_, 256, 256, 768, 0);
    // 3. self-attention
    attn_kernel<<<B_ * Q_ * NH_, 64, 0, stream>>>(Creg, E);
    // 4. out projection
    gemm_bias<<<dim3(MB, 4), 256, 0, stream>>>(E, out_proj_w, out_proj_b, F,
                                               NTOK_, 256, 256, 256, 0);
    // 5. LN1 (+ residual), and query = tgt + pos
    ln_kernel<<<NTOK_, 256, 0, stream>>>(tgt_text, F, ln1_g, ln1_b, A, pos, Bq);
    // 6. value projection
    gemm_bias<<<dim3(BS_ / BM, 4), 256, 0, stream>>>(src, vp_w, vp_b, Creg,
                                                     BS_, 256, 256, 256, 0);
    // 7. sampling offsets
    gemm_bias<<<dim3(MB, 4), 256, 0, stream>>>(Bq, samp_off_w, samp_off_b, D1,
                                               NTOK_, 256, 256, 256, 0);
    // 8. attention-weight logits
    gemm_bias<<<dim3(MB, 2), 256, 0, stream>>>(Bq, aw_w, aw_b, D2,
                                               NTOK_, 128, 256, 128, 0);
    // 9. deformable sampling (aw softmax fused)
    deform_kernel<<<NTOK_, 256, 0, stream>>>(Creg, D1, D2, refpts, E);
    // 10. output projection of cross-attn
    gemm_bias<<<dim3(MB, 4), 256, 0, stream>>>(E, op_w, op_b, F,
                                               NTOK_, 256, 256, 256, 0);
    // 11. LN2 (+ residual), in place on A
    ln_kernel<<<NTOK_, 256, 0, stream>>>(A, F, ln2_g, ln2_b, A, nullptr, nullptr);
    // 12. FFN1 + ReLU
    gemm_bias<<<dim3(MB, 16), 256, 0, stream>>>(A, ffn1_w, ffn1_b, Creg,
                                                NTOK_, DFF_, 256, DFF_, 1);
    // 13. FFN2
    gemm_bias<<<dim3(MB, 4), 256, 0, stream>>>(Creg, ffn2_w, ffn2_b, F,
                                               NTOK_, 256, DFF_, 256, 0);
    // 14. LN3 (+ residual) -> d_out
    ln_kernel<<<NTOK_, 256, 0, stream>>>(A, F, ln3_g, ln3_b, (float*)d_out, nullptr, nullptr);
}

// Round 2
// 668.576 us; speedup vs baseline: 1.3483x; 1.3483x over previous
//
#include <hip/hip_runtime.h>
#include <cstddef>

// Problem constants (static per reference)
#define B_ 2
#define Q_ 300
#define T_ 25
#define C_ 256
#define NH_ 8
#define NL_ 4
#define NP_ 4
#define HD_ 32
#define DFF_ 1024
#define LQ_ (Q_ * T_)           // 7500
#define NTOK_ (B_ * LQ_)        // 15000
#define S_ 21760                // sum of level sizes
#define BS_ (B_ * S_)           // 43520

typedef __bf16 bf16x8 __attribute__((ext_vector_type(8)));
typedef float floatx4 __attribute__((ext_vector_type(4)));

__device__ __forceinline__ unsigned short f2bf(float f) {
    unsigned u = __float_as_uint(f);
    unsigned r = (u + 0x7FFFu + ((u >> 16) & 1u)) >> 16;   // RNE
    return (unsigned short)r;
}

// ---------------- bf16-MFMA GEMM: C[M,N] = act(A[M,K] @ W[N,K]^T + bias[N]) ----------------
// Tile 128x128, BK=32, 256 threads (4 waves, 2x2 of 64x64 per-wave tiles).
// A fp32 / W fp32 converted to bf16 during LDS staging. N must be a multiple
// of 128 * grid-coverage (all Ns here are multiples of 128); K multiple of 32.
#define GBM 128
#define GBN 128
#define GBK 32
#define LDA_S 40   // LDS row stride in bf16 (pad 32 -> 40 to break bank stride)

__global__ __launch_bounds__(256) void gemm_bias(
    const float* __restrict__ A, const float* __restrict__ W,
    const float* __restrict__ bias, float* __restrict__ C,
    int M, int N, int K, int ldc, int relu)
{
    __shared__ unsigned short Asl[GBM * LDA_S];
    __shared__ unsigned short Bsl[GBN * LDA_S];

    const int m0 = blockIdx.x * GBM;
    const int n0 = blockIdx.y * GBN;
    const int t  = threadIdx.x;
    const int wid  = t >> 6;
    const int lane = t & 63;
    const int wm = (wid >> 1) * 64;    // wave tile origin in M
    const int wn = (wid & 1) * 64;     // wave tile origin in N
    const int fm = lane & 15;          // fragment row
    const int fq = (lane >> 4) * 8;    // fragment k-offset

    floatx4 acc[4][4];
    #pragma unroll
    for (int i = 0; i < 4; ++i)
        #pragma unroll
        for (int j = 0; j < 4; ++j)
            acc[i][j] = (floatx4){0.f, 0.f, 0.f, 0.f};

    for (int k0 = 0; k0 < K; k0 += GBK) {
        // stage A: 128x32 fp32 -> bf16.  1024 float4 chunks / 256 threads = 4 each
        #pragma unroll
        for (int i = 0; i < 4; ++i) {
            int idx = t + 256 * i;
            int row = idx >> 3;
            int c4  = (idx & 7) * 4;
            int gm = m0 + row;
            float4 v = make_float4(0.f, 0.f, 0.f, 0.f);
            if (gm < M) v = *(const float4*)(A + (size_t)gm * K + k0 + c4);
            uint2 p;
            p.x = (unsigned)f2bf(v.x) | ((unsigned)f2bf(v.y) << 16);
            p.y = (unsigned)f2bf(v.z) | ((unsigned)f2bf(v.w) << 16);
            *(uint2*)&Asl[row * LDA_S + c4] = p;
        }
        // stage W: 128x32 fp32 -> bf16 (no guard: N covered, K covered)
        #pragma unroll
        for (int i = 0; i < 4; ++i) {
            int idx = t + 256 * i;
            int row = idx >> 3;
            int c4  = (idx & 7) * 4;
            float4 v = *(const float4*)(W + (size_t)(n0 + row) * K + k0 + c4);
            uint2 p;
            p.x = (unsigned)f2bf(v.x) | ((unsigned)f2bf(v.y) << 16);
            p.y = (unsigned)f2bf(v.z) | ((unsigned)f2bf(v.w) << 16);
            *(uint2*)&Bsl[row * LDA_S + c4] = p;
        }
        __syncthreads();

        bf16x8 af[4], bf[4];
        #pragma unroll
        for (int i = 0; i < 4; ++i)
            af[i] = *(const bf16x8*)&Asl[(wm + i * 16 + fm) * LDA_S + fq];
        #pragma unroll
        for (int j = 0; j < 4; ++j)
            bf[j] = *(const bf16x8*)&Bsl[(wn + j * 16 + fm) * LDA_S + fq];

        #pragma unroll
        for (int i = 0; i < 4; ++i)
            #pragma unroll
            for (int j = 0; j < 4; ++j)
                acc[i][j] = __builtin_amdgcn_mfma_f32_16x16x32_bf16(af[i], bf[j], acc[i][j], 0, 0, 0);
        __syncthreads();
    }

    // epilogue: C/D layout col=lane&15, row=(lane>>4)*4+reg
    const int cr = (lane >> 4) * 4;
    const int cc = lane & 15;
    #pragma unroll
    for (int j = 0; j < 4; ++j) {
        int gn = n0 + wn + j * 16 + cc;
        float bia = bias[gn];
        #pragma unroll
        for (int i = 0; i < 4; ++i) {
            #pragma unroll
            for (int r = 0; r < 4; ++r) {
                int gm = m0 + wm + i * 16 + cr + r;
                if (gm < M) {
                    float v = acc[i][j][r] + bia;
                    if (relu) v = fmaxf(v, 0.f);
                    C[(size_t)gm * ldc + gn] = v;
                }
            }
        }
    }
}

// ---------------- elementwise add ----------------
__global__ __launch_bounds__(256) void add_kernel(
    const float* __restrict__ a, const float* __restrict__ b,
    float* __restrict__ o, int n)
{
    int i = blockIdx.x * 256 + threadIdx.x;
    if (i < n) o[i] = a[i] + b[i];
}

// ---------------- self-attention over T=25, one wave per (seq, head) ----------------
__global__ __launch_bounds__(64) void attn_kernel(
    const float* __restrict__ qkv,   // [NTOK, 768]: q|k|v per token
    float* __restrict__ o)           // [NTOK, 256]
{
    int sh = blockIdx.x;
    int s = sh >> 3, h = sh & 7;     // s in [0, 600), h in [0, 8)
    __shared__ float qs[T_][HD_], ks[T_][HD_], vs[T_][HD_];
    int t = threadIdx.x;

    for (int idx = t; idx < T_ * HD_; idx += 64) {
        int i = idx >> 5, d = idx & 31;
        size_t base = ((size_t)(s * T_ + i)) * 768 + h * HD_ + d;
        qs[i][d] = qkv[base];
        ks[i][d] = qkv[base + 256];
        vs[i][d] = qkv[base + 512];
    }
    __syncthreads();

    if (t < T_) {
        float sc[T_];
        float mx = -1e30f;
        #pragma unroll
        for (int j = 0; j < T_; ++j) {
            float dot = 0.f;
            #pragma unroll
            for (int d = 0; d < HD_; ++d) dot += qs[t][d] * ks[j][d];
            sc[j] = dot * 0.17677669529663687f;  // 1/sqrt(32)
            mx = fmaxf(mx, sc[j]);
        }
        float sum = 0.f;
        #pragma unroll
        for (int j = 0; j < T_; ++j) { sc[j] = __expf(sc[j] - mx); sum += sc[j]; }
        float inv = 1.f / sum;
        float out[HD_];
        #pragma unroll
        for (int d = 0; d < HD_; ++d) out[d] = 0.f;
        for (int j = 0; j < T_; ++j) {
            float p = sc[j] * inv;
            #pragma unroll
            for (int d = 0; d < HD_; ++d) out[d] += p * vs[j][d];
        }
        size_t ob = ((size_t)(s * T_ + t)) * C_ + h * HD_;
        #pragma unroll
        for (int d = 0; d < HD_; ++d) o[ob + d] = out[d];
    }
}

// ---------------- fused residual + LayerNorm (+ optional query = out + pos) ----------------
__global__ __launch_bounds__(256) void ln_kernel(
    const float* __restrict__ x, const float* __restrict__ r,
    const float* __restrict__ g, const float* __restrict__ b,
    float* __restrict__ out, const float* __restrict__ pos,
    float* __restrict__ qout)
{
    int tok = blockIdx.x;
    int t = threadIdx.x;
    size_t base = (size_t)tok * C_;
    float v = x[base + t] + r[base + t];

    float s = v, ss = v * v;
    #pragma unroll
    for (int off = 32; off; off >>= 1) {
        s += __shfl_down(s, off);
        ss += __shfl_down(ss, off);
    }
    __shared__ float ws[4], wss[4];
    __shared__ float mean_s, rstd_s;
    int wid = t >> 6, lane = t & 63;
    if (lane == 0) { ws[wid] = s; wss[wid] = ss; }
    __syncthreads();
    if (t == 0) {
        float S = 0.f, SS = 0.f;
        #pragma unroll
        for (int i = 0; i < 4; ++i) { S += ws[i]; SS += wss[i]; }
        float m = S / 256.f;
        float var = SS / 256.f - m * m;
        mean_s = m;
        rstd_s = rsqrtf(var + 1e-5f);
    }
    __syncthreads();
    float y = (v - mean_s) * rstd_s * g[t] + b[t];
    out[base + t] = y;
    if (qout) qout[base + t] = y + pos[base + t];
}

// ---------------- deformable sampling, 32 lanes per (token, head), aw-softmax fused ----------------
__global__ __launch_bounds__(256) void deform_kernel(
    const float* __restrict__ value,      // [B, S, NH, HD]
    const float* __restrict__ off,        // [NTOK, 256]
    const float* __restrict__ aw_logits,  // [NTOK, 128]
    const float* __restrict__ refpts,     // [B, LQ, NL, 2]
    float* __restrict__ out)              // [NTOK, 256] laid out (tok, h, d)
{
    int unit = blockIdx.x * 8 + (threadIdx.x >> 5);  // (tok, h)
    int d = threadIdx.x & 31;
    int h = unit & 7;
    int tok = unit >> 3;                 // b*LQ + lq
    int b = tok / LQ_;

    // softmax over 16 attention-weight logits (redundant per lane; broadcast loads)
    const float* awp = aw_logits + (size_t)tok * 128 + h * 16;
    float logit[16];
    float mx = -1e30f;
    #pragma unroll
    for (int i = 0; i < 16; ++i) { logit[i] = awp[i]; mx = fmaxf(mx, logit[i]); }
    float sum = 0.f;
    #pragma unroll
    for (int i = 0; i < 16; ++i) { logit[i] = __expf(logit[i] - mx); sum += logit[i]; }
    float inv = 1.f / sum;

    const float* offp = off + (size_t)tok * 256 + h * 32;
    const float* refp = refpts + (size_t)tok * (NL_ * 2);

    const int HW[4]     = {128, 64, 32, 16};
    const int starts[4] = {0, 16384, 20480, 21504};

    float acc = 0.f;
    #pragma unroll
    for (int l = 0; l < 4; ++l) {
        const int Hl = HW[l], Wl = HW[l];
        float rx = refp[l * 2 + 0], ry = refp[l * 2 + 1];
        const float* vbase = value + ((size_t)b * S_ + starts[l]) * (NH_ * HD_) + h * HD_ + d;
        #pragma unroll
        for (int p = 0; p < 4; ++p) {
            float ox = offp[(l * 4 + p) * 2 + 0];
            float oy = offp[(l * 4 + p) * 2 + 1];
            float xl = rx * (float)Wl + ox - 0.5f;
            float yl = ry * (float)Hl + oy - 0.5f;
            float x0f = floorf(xl), y0f = floorf(yl);
            int x0 = (int)x0f, y0 = (int)y0f;
            float wx1 = xl - x0f, wy1 = yl - y0f;
            float wx0 = 1.f - wx1, wy0 = 1.f - wy1;
            float aww = logit[l * 4 + p] * inv;

            float sv = 0.f;
            #pragma unroll
            for (int c = 0; c < 4; ++c) {
                int dx = c & 1, dy = c >> 1;
                int xi = x0 + dx, yi = y0 + dy;
                float w = (dx ? wx1 : wx0) * (dy ? wy1 : wy0);
                bool valid = (xi >= 0) & (xi < Wl) & (yi >= 0) & (yi < Hl);
                int xc = min(max(xi, 0), Wl - 1);
                int yc = min(max(yi, 0), Hl - 1);
                float gv = vbase[((size_t)(yc * Wl + xc)) * (NH_ * HD_)];
                sv += gv * (valid ? w : 0.f);
            }
            acc += aww * sv;
        }
    }
    out[(size_t)tok * C_ + h * HD_ + d] = acc;
}

// ---------------- host launch ----------------
extern "C" void kernel_launch(void* const* d_in, const int* in_sizes, int n_in,
                              void* d_out, int out_size, void* d_ws, size_t ws_size,
                              hipStream_t stream) {
    const float* tgt_text = (const float*)d_in[0];
    const float* pos      = (const float*)d_in[1];
    const float* refpts   = (const float*)d_in[2];
    const float* src      = (const float*)d_in[3];
    // d_in[4], d_in[5]: spatial shapes / level starts (static, unused)
    const float* in_proj_w  = (const float*)d_in[6];
    const float* in_proj_b  = (const float*)d_in[7];
    const float* out_proj_w = (const float*)d_in[8];
    const float* out_proj_b = (const float*)d_in[9];
    const float* ln1_g = (const float*)d_in[10];
    const float* ln1_b = (const float*)d_in[11];
    const float* samp_off_w = (const float*)d_in[12];
    const float* samp_off_b = (const float*)d_in[13];
    const float* aw_w = (const float*)d_in[14];
    const float* aw_b = (const float*)d_in[15];
    const float* vp_w = (const float*)d_in[16];
    const float* vp_b = (const float*)d_in[17];
    const float* op_w = (const float*)d_in[18];
    const float* op_b = (const float*)d_in[19];
    const float* ln2_g = (const float*)d_in[20];
    const float* ln2_b = (const float*)d_in[21];
    const float* ffn1_w = (const float*)d_in[22];
    const float* ffn1_b = (const float*)d_in[23];
    const float* ffn2_w = (const float*)d_in[24];
    const float* ffn2_b = (const float*)d_in[25];
    const float* ln3_g = (const float*)d_in[26];
    const float* ln3_b = (const float*)d_in[27];

    const size_t NC = (size_t)NTOK_ * C_;      // 3,840,000
    float* ws = (float*)d_ws;
    float* A    = ws;                 // [NTOK,C]   tgt (post-LN1, post-LN2)
    float* Bq   = ws + NC;            // [NTOK,C]   qk input / query
    float* Creg = ws + 2 * NC;        // 15,360,000 floats: qkv -> value -> ffn hidden
    float* D1   = Creg + (size_t)NTOK_ * DFF_;       // [NTOK,256] sampling offsets
    float* D2   = D1 + NC;                            // [NTOK,128] aw logits
    float* E    = D2 + (size_t)NTOK_ * 128;           // [NTOK,C]   attn out / deform accum
    float* F    = E + NC;                             // [NTOK,C]   tgt2 / cross / ffn2

    const int MB  = (NTOK_ + GBM - 1) / GBM;   // 118
    const int MBV = BS_ / GBM;                 // 340

    // 1. qk input = tgt + pos
    add_kernel<<<(int)((NC + 255) / 256), 256, 0, stream>>>(tgt_text, pos, Bq, (int)NC);
    // 2. QK projection (cols 0..511 of qkv), V projection (cols 512..767)
    gemm_bias<<<dim3(MB, 4), 256, 0, stream>>>(Bq, in_proj_w, in_proj_b, Creg,
                                               NTOK_, 512, 256, 768, 0);
    gemm_bias<<<dim3(MB, 2), 256, 0, stream>>>(tgt_text, in_proj_w + 512 * 256, in_proj_b + 512,
                                               Creg + 512, NTOK_, 256, 256, 768, 0);
    // 3. self-attention
    attn_kernel<<<B_ * Q_ * NH_, 64, 0, stream>>>(Creg, E);
    // 4. out projection
    gemm_bias<<<dim3(MB, 2), 256, 0, stream>>>(E, out_proj_w, out_proj_b, F,
                                               NTOK_, 256, 256, 256, 0);
    // 5. LN1 (+ residual), and query = tgt + pos
    ln_kernel<<<NTOK_, 256, 0, stream>>>(tgt_text, F, ln1_g, ln1_b, A, pos, Bq);
    // 6. value projection
    gemm_bias<<<dim3(MBV, 2), 256, 0, stream>>>(src, vp_w, vp_b, Creg,
                                                BS_, 256, 256, 256, 0);
    // 7. sampling offsets
    gemm_bias<<<dim3(MB, 2), 256, 0, stream>>>(Bq, samp_off_w, samp_off_b, D1,
                                               NTOK_, 256, 256, 256, 0);
    // 8. attention-weight logits
    gemm_bias<<<dim3(MB, 1), 256, 0, stream>>>(Bq, aw_w, aw_b, D2,
                                               NTOK_, 128, 256, 128, 0);
    // 9. deformable sampling (aw softmax fused)
    deform_kernel<<<NTOK_, 256, 0, stream>>>(Creg, D1, D2, refpts, E);
    // 10. output projection of cross-attn
    gemm_bias<<<dim3(MB, 2), 256, 0, stream>>>(E, op_w, op_b, F,
                                               NTOK_, 256, 256, 256, 0);
    // 11. LN2 (+ residual), in place on A
    ln_kernel<<<NTOK_, 256, 0, stream>>>(A, F, ln2_g, ln2_b, A, nullptr, nullptr);
    // 12. FFN1 + ReLU
    gemm_bias<<<dim3(MB, 8), 256, 0, stream>>>(A, ffn1_w, ffn1_b, Creg,
                                               NTOK_, DFF_, 256, DFF_, 1);
    // 13. FFN2
    gemm_bias<<<dim3(MB, 2), 256, 0, stream>>>(Creg, ffn2_w, ffn2_b, F,
                                               NTOK_, 256, DFF_, 256, 0);
    // 14. LN3 (+ residual) -> d_out
    ln_kernel<<<NTOK_, 256, 0, stream>>>(A, F, ln3_g, ln3_b, (float*)d_out, nullptr, nullptr);
}

// Round 3
// 607.350 us; speedup vs baseline: 1.4842x; 1.1008x over previous
//
#include <hip/hip_runtime.h>
#include <cstddef>

// Problem constants (static per reference)
#define B_ 2
#define Q_ 300
#define T_ 25
#define C_ 256
#define NH_ 8
#define NL_ 4
#define NP_ 4
#define HD_ 32
#define DFF_ 1024
#define LQ_ (Q_ * T_)           // 7500
#define NTOK_ (B_ * LQ_)        // 15000
#define S_ 21760                // sum of level sizes
#define BS_ (B_ * S_)           // 43520

typedef __bf16 bf16x8 __attribute__((ext_vector_type(8)));
typedef float floatx4 __attribute__((ext_vector_type(4)));

__device__ __forceinline__ unsigned short f2bf(float f) {
    unsigned u = __float_as_uint(f);
    unsigned r = (u + 0x7FFFu + ((u >> 16) & 1u)) >> 16;   // RNE
    return (unsigned short)r;
}

// ---------------- bf16-MFMA GEMM: C[M,N] = act((A1+A2)[M,K] @ W[N,K]^T + bias[N]) ----------------
// Tile 128x128, BK=32, 256 threads (4 waves, 2x2 of 64x64 per-wave tiles).
// A fp32 (optionally summed with A2) / W fp32, converted to bf16 during LDS
// staging. N multiple of 128 via grid; K multiple of 32.
#define GBM 128
#define GBN 128
#define GBK 32
#define LDA_S 40   // LDS row stride in bf16 (pad 32 -> 40 to break bank stride)

__global__ __launch_bounds__(256) void gemm_bias(
    const float* __restrict__ A, const float* __restrict__ A2,
    const float* __restrict__ W,
    const float* __restrict__ bias, float* __restrict__ C,
    int M, int N, int K, int ldc, int relu)
{
    __shared__ unsigned short Asl[GBM * LDA_S];
    __shared__ unsigned short Bsl[GBN * LDA_S];

    const int m0 = blockIdx.x * GBM;
    const int n0 = blockIdx.y * GBN;
    const int t  = threadIdx.x;
    const int wid  = t >> 6;
    const int lane = t & 63;
    const int wm = (wid >> 1) * 64;    // wave tile origin in M
    const int wn = (wid & 1) * 64;     // wave tile origin in N
    const int fm = lane & 15;          // fragment row
    const int fq = (lane >> 4) * 8;    // fragment k-offset

    floatx4 acc[4][4];
    #pragma unroll
    for (int i = 0; i < 4; ++i)
        #pragma unroll
        for (int j = 0; j < 4; ++j)
            acc[i][j] = (floatx4){0.f, 0.f, 0.f, 0.f};

    for (int k0 = 0; k0 < K; k0 += GBK) {
        // stage A: 128x32 fp32 -> bf16.  1024 float4 chunks / 256 threads = 4 each
        #pragma unroll
        for (int i = 0; i < 4; ++i) {
            int idx = t + 256 * i;
            int row = idx >> 3;
            int c4  = (idx & 7) * 4;
            int gm = m0 + row;
            float4 v = make_float4(0.f, 0.f, 0.f, 0.f);
            if (gm < M) {
                v = *(const float4*)(A + (size_t)gm * K + k0 + c4);
                if (A2) {
                    float4 v2 = *(const float4*)(A2 + (size_t)gm * K + k0 + c4);
                    v.x += v2.x; v.y += v2.y; v.z += v2.z; v.w += v2.w;
                }
            }
            uint2 p;
            p.x = (unsigned)f2bf(v.x) | ((unsigned)f2bf(v.y) << 16);
            p.y = (unsigned)f2bf(v.z) | ((unsigned)f2bf(v.w) << 16);
            *(uint2*)&Asl[row * LDA_S + c4] = p;
        }
        // stage W: 128x32 fp32 -> bf16 (no guard: N covered, K covered)
        #pragma unroll
        for (int i = 0; i < 4; ++i) {
            int idx = t + 256 * i;
            int row = idx >> 3;
            int c4  = (idx & 7) * 4;
            float4 v = *(const float4*)(W + (size_t)(n0 + row) * K + k0 + c4);
            uint2 p;
            p.x = (unsigned)f2bf(v.x) | ((unsigned)f2bf(v.y) << 16);
            p.y = (unsigned)f2bf(v.z) | ((unsigned)f2bf(v.w) << 16);
            *(uint2*)&Bsl[row * LDA_S + c4] = p;
        }
        __syncthreads();

        bf16x8 af[4], bf[4];
        #pragma unroll
        for (int i = 0; i < 4; ++i)
            af[i] = *(const bf16x8*)&Asl[(wm + i * 16 + fm) * LDA_S + fq];
        #pragma unroll
        for (int j = 0; j < 4; ++j)
            bf[j] = *(const bf16x8*)&Bsl[(wn + j * 16 + fm) * LDA_S + fq];

        #pragma unroll
        for (int i = 0; i < 4; ++i)
            #pragma unroll
            for (int j = 0; j < 4; ++j)
                acc[i][j] = __builtin_amdgcn_mfma_f32_16x16x32_bf16(af[i], bf[j], acc[i][j], 0, 0, 0);
        __syncthreads();
    }

    // epilogue: C/D layout col=lane&15, row=(lane>>4)*4+reg
    const int cr = (lane >> 4) * 4;
    const int cc = lane & 15;
    #pragma unroll
    for (int j = 0; j < 4; ++j) {
        int gn = n0 + wn + j * 16 + cc;
        float bia = bias[gn];
        #pragma unroll
        for (int i = 0; i < 4; ++i) {
            #pragma unroll
            for (int r = 0; r < 4; ++r) {
                int gm = m0 + wm + i * 16 + cr + r;
                if (gm < M) {
                    float v = acc[i][j][r] + bia;
                    if (relu) v = fmaxf(v, 0.f);
                    C[(size_t)gm * ldc + gn] = v;
                }
            }
        }
    }
}

// ---------------- self-attention over T=25, one wave per (seq, head) ----------------
__global__ __launch_bounds__(64) void attn_kernel(
    const float* __restrict__ qkv,   // [NTOK, 768]: q|k|v per token
    float* __restrict__ o)           // [NTOK, 256]
{
    int sh = blockIdx.x;
    int s = sh >> 3, h = sh & 7;     // s in [0, 600), h in [0, 8)
    __shared__ float qs[T_][HD_], ks[T_][HD_], vs[T_][HD_];
    int t = threadIdx.x;

    for (int idx = t; idx < T_ * HD_; idx += 64) {
        int i = idx >> 5, d = idx & 31;
        size_t base = ((size_t)(s * T_ + i)) * 768 + h * HD_ + d;
        qs[i][d] = qkv[base];
        ks[i][d] = qkv[base + 256];
        vs[i][d] = qkv[base + 512];
    }
    __syncthreads();

    if (t < T_) {
        float sc[T_];
        float mx = -1e30f;
        #pragma unroll
        for (int j = 0; j < T_; ++j) {
            float dot = 0.f;
            #pragma unroll
            for (int d = 0; d < HD_; ++d) dot += qs[t][d] * ks[j][d];
            sc[j] = dot * 0.17677669529663687f;  // 1/sqrt(32)
            mx = fmaxf(mx, sc[j]);
        }
        float sum = 0.f;
        #pragma unroll
        for (int j = 0; j < T_; ++j) { sc[j] = __expf(sc[j] - mx); sum += sc[j]; }
        float inv = 1.f / sum;
        float out[HD_];
        #pragma unroll
        for (int d = 0; d < HD_; ++d) out[d] = 0.f;
        for (int j = 0; j < T_; ++j) {
            float p = sc[j] * inv;
            #pragma unroll
            for (int d = 0; d < HD_; ++d) out[d] += p * vs[j][d];
        }
        size_t ob = ((size_t)(s * T_ + t)) * C_ + h * HD_;
        #pragma unroll
        for (int d = 0; d < HD_; ++d) o[ob + d] = out[d];
    }
}

// ---------------- fused residual + LayerNorm (+ optional query = out + pos) ----------------
__global__ __launch_bounds__(256) void ln_kernel(
    const float* __restrict__ x, const float* __restrict__ r,
    const float* __restrict__ g, const float* __restrict__ b,
    float* __restrict__ out, const float* __restrict__ pos,
    float* __restrict__ qout)
{
    int tok = blockIdx.x;
    int t = threadIdx.x;
    size_t base = (size_t)tok * C_;
    float v = x[base + t] + r[base + t];

    float s = v, ss = v * v;
    #pragma unroll
    for (int off = 32; off; off >>= 1) {
        s += __shfl_down(s, off);
        ss += __shfl_down(ss, off);
    }
    __shared__ float ws[4], wss[4];
    __shared__ float mean_s, rstd_s;
    int wid = t >> 6, lane = t & 63;
    if (lane == 0) { ws[wid] = s; wss[wid] = ss; }
    __syncthreads();
    if (t == 0) {
        float S = 0.f, SS = 0.f;
        #pragma unroll
        for (int i = 0; i < 4; ++i) { S += ws[i]; SS += wss[i]; }
        float m = S / 256.f;
        float var = SS / 256.f - m * m;
        mean_s = m;
        rstd_s = rsqrtf(var + 1e-5f);
    }
    __syncthreads();
    float y = (v - mean_s) * rstd_s * g[t] + b[t];
    out[base + t] = y;
    if (qout) qout[base + t] = y + pos[base + t];
}

// ---------------- deformable sampling: one wave per token, 8 lanes per head (float4) ----------------
__global__ __launch_bounds__(256) void deform_kernel(
    const float* __restrict__ value,      // [B, S, NH, HD]
    const float* __restrict__ off,        // [NTOK, 256]
    const float* __restrict__ aw_logits,  // [NTOK, 128]
    const float* __restrict__ refpts,     // [B, LQ, NL, 2]
    float* __restrict__ out)              // [NTOK, 256] laid out (tok, h, d)
{
    const int tok = (blockIdx.x * 256 + threadIdx.x) >> 6;   // one wave per token
    const int lane = threadIdx.x & 63;
    const int h  = lane >> 3;          // head 0..7
    const int d4 = (lane & 7) * 4;     // channel offset 0,4,...,28
    const int b = tok / LQ_;

    // softmax over 16 attention-weight logits (redundant across the 8 lanes of a head)
    const float* awp = aw_logits + (size_t)tok * 128 + h * 16;
    float logit[16];
    float mx = -1e30f;
    #pragma unroll
    for (int i = 0; i < 16; ++i) { logit[i] = awp[i]; mx = fmaxf(mx, logit[i]); }
    float sum = 0.f;
    #pragma unroll
    for (int i = 0; i < 16; ++i) { logit[i] = __expf(logit[i] - mx); sum += logit[i]; }
    float inv = 1.f / sum;

    const float* offp = off + (size_t)tok * 256 + h * 32;
    const float* refp = refpts + (size_t)tok * (NL_ * 2);

    const int HW[4]     = {128, 64, 32, 16};
    const int starts[4] = {0, 16384, 20480, 21504};

    floatx4 acc = (floatx4){0.f, 0.f, 0.f, 0.f};
    #pragma unroll
    for (int l = 0; l < 4; ++l) {
        const int Hl = HW[l], Wl = HW[l];
        float rx = refp[l * 2 + 0], ry = refp[l * 2 + 1];
        const float* vbase = value + ((size_t)b * S_ + starts[l]) * (NH_ * HD_) + h * HD_ + d4;
        #pragma unroll
        for (int p = 0; p < 4; ++p) {
            float ox = offp[(l * 4 + p) * 2 + 0];
            float oy = offp[(l * 4 + p) * 2 + 1];
            float xl = rx * (float)Wl + ox - 0.5f;
            float yl = ry * (float)Hl + oy - 0.5f;
            float x0f = floorf(xl), y0f = floorf(yl);
            int x0 = (int)x0f, y0 = (int)y0f;
            float wx1 = xl - x0f, wy1 = yl - y0f;
            float wx0 = 1.f - wx1, wy0 = 1.f - wy1;
            float aww = logit[l * 4 + p] * inv;

            floatx4 sv = (floatx4){0.f, 0.f, 0.f, 0.f};
            #pragma unroll
            for (int c = 0; c < 4; ++c) {
                int dx = c & 1, dy = c >> 1;
                int xi = x0 + dx, yi = y0 + dy;
                float w = (dx ? wx1 : wx0) * (dy ? wy1 : wy0);
                bool valid = (xi >= 0) & (xi < Wl) & (yi >= 0) & (yi < Hl);
                int xc = min(max(xi, 0), Wl - 1);
                int yc = min(max(yi, 0), Hl - 1);
                floatx4 gv = *(const floatx4*)(vbase + ((size_t)(yc * Wl + xc)) * (NH_ * HD_));
                float wv = valid ? w : 0.f;
                sv += gv * wv;
            }
            acc += sv * aww;
        }
    }
    *(floatx4*)(out + (size_t)tok * C_ + lane * 4) = acc;
}

// ---------------- host launch ----------------
extern "C" void kernel_launch(void* const* d_in, const int* in_sizes, int n_in,
                              void* d_out, int out_size, void* d_ws, size_t ws_size,
                              hipStream_t stream) {
    const float* tgt_text = (const float*)d_in[0];
    const float* pos      = (const float*)d_in[1];
    const float* refpts   = (const float*)d_in[2];
    const float* src      = (const float*)d_in[3];
    // d_in[4], d_in[5]: spatial shapes / level starts (static, unused)
    const float* in_proj_w  = (const float*)d_in[6];
    const float* in_proj_b  = (const float*)d_in[7];
    const float* out_proj_w = (const float*)d_in[8];
    const float* out_proj_b = (const float*)d_in[9];
    const float* ln1_g = (const float*)d_in[10];
    const float* ln1_b = (const float*)d_in[11];
    const float* samp_off_w = (const float*)d_in[12];
    const float* samp_off_b = (const float*)d_in[13];
    const float* aw_w = (const float*)d_in[14];
    const float* aw_b = (const float*)d_in[15];
    const float* vp_w = (const float*)d_in[16];
    const float* vp_b = (const float*)d_in[17];
    const float* op_w = (const float*)d_in[18];
    const float* op_b = (const float*)d_in[19];
    const float* ln2_g = (const float*)d_in[20];
    const float* ln2_b = (const float*)d_in[21];
    const float* ffn1_w = (const float*)d_in[22];
    const float* ffn1_b = (const float*)d_in[23];
    const float* ffn2_w = (const float*)d_in[24];
    const float* ffn2_b = (const float*)d_in[25];
    const float* ln3_g = (const float*)d_in[26];
    const float* ln3_b = (const float*)d_in[27];

    const size_t NC = (size_t)NTOK_ * C_;      // 3,840,000
    float* ws = (float*)d_ws;
    float* A    = ws;                 // [NTOK,C]   tgt (post-LN1, post-LN2)
    float* Bq   = ws + NC;            // [NTOK,C]   query (tgt+pos after LN1)
    float* Creg = ws + 2 * NC;        // 15,360,000 floats: qkv -> value -> ffn hidden
    float* D1   = Creg + (size_t)NTOK_ * DFF_;       // [NTOK,256] sampling offsets
    float* D2   = D1 + NC;                            // [NTOK,128] aw logits
    float* E    = D2 + (size_t)NTOK_ * 128;           // [NTOK,C]   attn out / deform accum
    float* F    = E + NC;                             // [NTOK,C]   tgt2 / cross / ffn2

    const int MB  = (NTOK_ + GBM - 1) / GBM;   // 118
    const int MBV = BS_ / GBM;                 // 340

    // 1. QK projection on (tgt+pos) fused; V projection on tgt
    gemm_bias<<<dim3(MB, 4), 256, 0, stream>>>(tgt_text, pos, in_proj_w, in_proj_b, Creg,
                                               NTOK_, 512, 256, 768, 0);
    gemm_bias<<<dim3(MB, 2), 256, 0, stream>>>(tgt_text, nullptr, in_proj_w + 512 * 256,
                                               in_proj_b + 512, Creg + 512, NTOK_, 256, 256, 768, 0);
    // 2. self-attention
    attn_kernel<<<B_ * Q_ * NH_, 64, 0, stream>>>(Creg, E);
    // 3. out projection
    gemm_bias<<<dim3(MB, 2), 256, 0, stream>>>(E, nullptr, out_proj_w, out_proj_b, F,
                                               NTOK_, 256, 256, 256, 0);
    // 4. LN1 (+ residual), and query = tgt + pos
    ln_kernel<<<NTOK_, 256, 0, stream>>>(tgt_text, F, ln1_g, ln1_b, A, pos, Bq);
    // 5. value projection
    gemm_bias<<<dim3(MBV, 2), 256, 0, stream>>>(src, nullptr, vp_w, vp_b, Creg,
                                                BS_, 256, 256, 256, 0);
    // 6. sampling offsets
    gemm_bias<<<dim3(MB, 2), 256, 0, stream>>>(Bq, nullptr, samp_off_w, samp_off_b, D1,
                                               NTOK_, 256, 256, 256, 0);
    // 7. attention-weight logits
    gemm_bias<<<dim3(MB, 1), 256, 0, stream>>>(Bq, nullptr, aw_w, aw_b, D2,
                                               NTOK_, 128, 256, 128, 0);
    // 8. deformable sampling (aw softmax fused); one wave per token
    deform_kernel<<<NTOK_ / 4, 256, 0, stream>>>(Creg, D1, D2, refpts, E);
    // 9. output projection of cross-attn
    gemm_bias<<<dim3(MB, 2), 256, 0, stream>>>(E, nullptr, op_w, op_b, F,
                                               NTOK_, 256, 256, 256, 0);
    // 10. LN2 (+ residual), in place on A
    ln_kernel<<<NTOK_, 256, 0, stream>>>(A, F, ln2_g, ln2_b, A, nullptr, nullptr);
    // 11. FFN1 + ReLU
    gemm_bias<<<dim3(MB, 8), 256, 0, stream>>>(A, nullptr, ffn1_w, ffn1_b, Creg,
                                               NTOK_, DFF_, 256, DFF_, 1);
    // 12. FFN2
    gemm_bias<<<dim3(MB, 2), 256, 0, stream>>>(Creg, nullptr, ffn2_w, ffn2_b, F,
                                               NTOK_, 256, DFF_, 256, 0);
    // 13. LN3 (+ residual) -> d_out
    ln_kernel<<<NTOK_, 256, 0, stream>>>(A, F, ln3_g, ln3_b, (float*)d_out, nullptr, nullptr);
}

// Round 4
// 517.466 us; speedup vs baseline: 1.7420x; 1.1737x over previous
//
#include <hip/hip_runtime.h>
#include <cstddef>

// Problem constants (static per reference)
#define B_ 2
#define Q_ 300
#define T_ 25
#define C_ 256
#define NH_ 8
#define NL_ 4
#define NP_ 4
#define HD_ 32
#define DFF_ 1024
#define LQ_ (Q_ * T_)           // 7500
#define NTOK_ (B_ * LQ_)        // 15000
#define S_ 21760                // sum of level sizes
#define BS_ (B_ * S_)           // 43520

typedef __bf16 bf16x8 __attribute__((ext_vector_type(8)));
typedef float floatx4 __attribute__((ext_vector_type(4)));

// round-half-up bf16 pack: lo16 = bf16(x), hi16 = bf16(y). Compiler folds to v_perm.
__device__ __forceinline__ unsigned pack_bf16(float x, float y) {
    unsigned ux = __float_as_uint(x) + 0x8000u;
    unsigned uy = __float_as_uint(y) + 0x8000u;
    return (ux >> 16) | (uy & 0xFFFF0000u);
}

// ---------------- bf16-MFMA GEMM with register prefetch, optional A2 add, dual-W, split-K ----
// C[M,N] = act((A1+A2)[M,K] @ W[N,K]^T + bias[N]); W rows >= N1 come from W2/bias2.
// Tile 128x128, BK=32, 256 threads (4 waves, 2x2 of 64x64 wave tiles).
// Split-K: blockIdx.z covers K-range [z*kChunk, min(K,(z+1)*kChunk)); partial z
// writes to C + z*partStride (floats, signed); bias added only by z==0.
#define GBM 128
#define GBN 128
#define GBK 32
#define LDA_S 40   // LDS row stride in bf16 (pad 32 -> 40 to break bank stride)

__global__ __launch_bounds__(256) void gemm_bias(
    const float* __restrict__ A, const float* __restrict__ A2,
    const float* __restrict__ W, const float* __restrict__ W2, int N1,
    const float* __restrict__ bias, const float* __restrict__ bias2,
    float* __restrict__ C, long long partStride,
    int M, int N, int K, int kChunk, int ldc, int relu)
{
    __shared__ unsigned short Asl[GBM * LDA_S];
    __shared__ unsigned short Bsl[GBN * LDA_S];

    const int m0 = blockIdx.x * GBM;
    const int n0 = blockIdx.y * GBN;
    const int z  = blockIdx.z;
    const int kbeg = z * kChunk;
    const int kend = min(K, kbeg + kChunk);
    float* Cp = C + (long long)z * partStride;

    const int t  = threadIdx.x;
    const int wid  = t >> 6;
    const int lane = t & 63;
    const int wm = (wid >> 1) * 64;    // wave tile origin in M
    const int wn = (wid & 1) * 64;     // wave tile origin in N
    const int fm = lane & 15;          // fragment row
    const int fq = (lane >> 4) * 8;    // fragment k-offset

    floatx4 acc[4][4];
    #pragma unroll
    for (int i = 0; i < 4; ++i)
        #pragma unroll
        for (int j = 0; j < 4; ++j)
            acc[i][j] = (floatx4){0.f, 0.f, 0.f, 0.f};

    float4 pa[4], pw[4];
    auto load_tiles = [&](int k0) {
        #pragma unroll
        for (int i = 0; i < 4; ++i) {
            int idx = t + 256 * i;
            int row = idx >> 3;
            int c4  = (idx & 7) * 4;
            int gm = m0 + row;
            float4 v = make_float4(0.f, 0.f, 0.f, 0.f);
            if (gm < M) {
                v = *(const float4*)(A + (size_t)gm * K + k0 + c4);
                if (A2) {
                    float4 v2 = *(const float4*)(A2 + (size_t)gm * K + k0 + c4);
                    v.x += v2.x; v.y += v2.y; v.z += v2.z; v.w += v2.w;
                }
            }
            pa[i] = v;
            int gn = n0 + row;
            const float* wr = (W2 && gn >= N1) ? (W2 + (size_t)(gn - N1) * K)
                                               : (W + (size_t)gn * K);
            pw[i] = *(const float4*)(wr + k0 + c4);
        }
    };

    load_tiles(kbeg);
    for (int k0 = kbeg; k0 < kend; k0 += GBK) {
        // commit prefetched tile to LDS (fp32 -> bf16 pack)
        #pragma unroll
        for (int i = 0; i < 4; ++i) {
            int idx = t + 256 * i;
            int row = idx >> 3;
            int c4  = (idx & 7) * 4;
            uint2 p;
            p.x = pack_bf16(pa[i].x, pa[i].y);
            p.y = pack_bf16(pa[i].z, pa[i].w);
            *(uint2*)&Asl[row * LDA_S + c4] = p;
            uint2 q;
            q.x = pack_bf16(pw[i].x, pw[i].y);
            q.y = pack_bf16(pw[i].z, pw[i].w);
            *(uint2*)&Bsl[row * LDA_S + c4] = q;
        }
        __syncthreads();

        // issue next tile's global loads; they complete during the MFMAs below
        if (k0 + GBK < kend) load_tiles(k0 + GBK);

        bf16x8 af[4], bfr[4];
        #pragma unroll
        for (int i = 0; i < 4; ++i)
            af[i] = *(const bf16x8*)&Asl[(wm + i * 16 + fm) * LDA_S + fq];
        #pragma unroll
        for (int j = 0; j < 4; ++j)
            bfr[j] = *(const bf16x8*)&Bsl[(wn + j * 16 + fm) * LDA_S + fq];

        #pragma unroll
        for (int i = 0; i < 4; ++i)
            #pragma unroll
            for (int j = 0; j < 4; ++j)
                acc[i][j] = __builtin_amdgcn_mfma_f32_16x16x32_bf16(af[i], bfr[j], acc[i][j], 0, 0, 0);
        __syncthreads();
    }

    // epilogue: C/D layout col=lane&15, row=(lane>>4)*4+reg
    const int cr = (lane >> 4) * 4;
    const int cc = lane & 15;
    #pragma unroll
    for (int j = 0; j < 4; ++j) {
        int gn = n0 + wn + j * 16 + cc;
        float bia = 0.f;
        if (z == 0) bia = (bias2 && gn >= N1) ? bias2[gn - N1] : bias[gn];
        #pragma unroll
        for (int i = 0; i < 4; ++i) {
            #pragma unroll
            for (int r = 0; r < 4; ++r) {
                int gm = m0 + wm + i * 16 + cr + r;
                if (gm < M) {
                    float v = acc[i][j][r] + bia;
                    if (relu) v = fmaxf(v, 0.f);
                    Cp[(size_t)gm * ldc + gn] = v;
                }
            }
        }
    }
}

// ---------------- self-attention over T=25, one wave per (seq, head) ----------------
__global__ __launch_bounds__(64) void attn_kernel(
    const float* __restrict__ qkv,   // [NTOK, 768]: q|k|v per token
    float* __restrict__ o)           // [NTOK, 256]
{
    int sh = blockIdx.x;
    int s = sh >> 3, h = sh & 7;     // s in [0, 600), h in [0, 8)
    __shared__ float qs[T_][HD_], ks[T_][HD_], vs[T_][HD_];
    int t = threadIdx.x;

    for (int idx = t; idx < T_ * HD_; idx += 64) {
        int i = idx >> 5, d = idx & 31;
        size_t base = ((size_t)(s * T_ + i)) * 768 + h * HD_ + d;
        qs[i][d] = qkv[base];
        ks[i][d] = qkv[base + 256];
        vs[i][d] = qkv[base + 512];
    }
    __syncthreads();

    if (t < T_) {
        float sc[T_];
        float mx = -1e30f;
        #pragma unroll
        for (int j = 0; j < T_; ++j) {
            float dot = 0.f;
            #pragma unroll
            for (int d = 0; d < HD_; ++d) dot += qs[t][d] * ks[j][d];
            sc[j] = dot * 0.17677669529663687f;  // 1/sqrt(32)
            mx = fmaxf(mx, sc[j]);
        }
        float sum = 0.f;
        #pragma unroll
        for (int j = 0; j < T_; ++j) { sc[j] = __expf(sc[j] - mx); sum += sc[j]; }
        float inv = 1.f / sum;
        float out[HD_];
        #pragma unroll
        for (int d = 0; d < HD_; ++d) out[d] = 0.f;
        for (int j = 0; j < T_; ++j) {
            float p = sc[j] * inv;
            #pragma unroll
            for (int d = 0; d < HD_; ++d) out[d] += p * vs[j][d];
        }
        size_t ob = ((size_t)(s * T_ + t)) * C_ + h * HD_;
        #pragma unroll
        for (int d = 0; d < HD_; ++d) o[ob + d] = out[d];
    }
}

// ---------------- fused residual + LayerNorm; r = sum of nparts partials ----------------
__global__ __launch_bounds__(256) void ln_kernel(
    const float* __restrict__ x, const float* __restrict__ r,
    int nparts, long long rstride,
    const float* __restrict__ g, const float* __restrict__ b,
    float* __restrict__ out, const float* __restrict__ pos,
    float* __restrict__ qout)
{
    int tok = blockIdx.x;
    int t = threadIdx.x;
    size_t base = (size_t)tok * C_;
    float v = x[base + t];
    for (int p = 0; p < nparts; ++p)
        v += r[(long long)base + t + (long long)p * rstride];

    float s = v, ss = v * v;
    #pragma unroll
    for (int off = 32; off; off >>= 1) {
        s += __shfl_down(s, off);
        ss += __shfl_down(ss, off);
    }
    __shared__ float ws[4], wss[4];
    __shared__ float mean_s, rstd_s;
    int wid = t >> 6, lane = t & 63;
    if (lane == 0) { ws[wid] = s; wss[wid] = ss; }
    __syncthreads();
    if (t == 0) {
        float S = 0.f, SS = 0.f;
        #pragma unroll
        for (int i = 0; i < 4; ++i) { S += ws[i]; SS += wss[i]; }
        float m = S / 256.f;
        float var = SS / 256.f - m * m;
        mean_s = m;
        rstd_s = rsqrtf(var + 1e-5f);
    }
    __syncthreads();
    float y = (v - mean_s) * rstd_s * g[t] + b[t];
    out[base + t] = y;
    if (qout) qout[base + t] = y + pos[base + t];
}

// ---------------- deformable sampling: one wave per token, 8 lanes per head (float4) ----------------
// D12 combined buffer: [NTOK, 384] = offsets (cols 0..255) | aw logits (cols 256..383)
__global__ __launch_bounds__(256) void deform_kernel(
    const float* __restrict__ value,      // [B, S, NH, HD]
    const float* __restrict__ d12,        // [NTOK, 384]
    const float* __restrict__ refpts,     // [B, LQ, NL, 2]
    float* __restrict__ out)              // [NTOK, 256] laid out (tok, h, d)
{
    const int tok = (blockIdx.x * 256 + threadIdx.x) >> 6;   // one wave per token
    const int lane = threadIdx.x & 63;
    const int h  = lane >> 3;          // head 0..7
    const int d4 = (lane & 7) * 4;     // channel offset 0,4,...,28
    const int b = tok / LQ_;

    const float* awp = d12 + (size_t)tok * 384 + 256 + h * 16;
    float logit[16];
    float mx = -1e30f;
    #pragma unroll
    for (int i = 0; i < 16; ++i) { logit[i] = awp[i]; mx = fmaxf(mx, logit[i]); }
    float sum = 0.f;
    #pragma unroll
    for (int i = 0; i < 16; ++i) { logit[i] = __expf(logit[i] - mx); sum += logit[i]; }
    float inv = 1.f / sum;

    const float* offp = d12 + (size_t)tok * 384 + h * 32;
    const float* refp = refpts + (size_t)tok * (NL_ * 2);

    const int HW[4]     = {128, 64, 32, 16};
    const int starts[4] = {0, 16384, 20480, 21504};

    floatx4 acc = (floatx4){0.f, 0.f, 0.f, 0.f};
    #pragma unroll
    for (int l = 0; l < 4; ++l) {
        const int Hl = HW[l], Wl = HW[l];
        float rx = refp[l * 2 + 0], ry = refp[l * 2 + 1];
        const float* vbase = value + ((size_t)b * S_ + starts[l]) * (NH_ * HD_) + h * HD_ + d4;
        #pragma unroll
        for (int p = 0; p < 4; ++p) {
            float ox = offp[(l * 4 + p) * 2 + 0];
            float oy = offp[(l * 4 + p) * 2 + 1];
            float xl = rx * (float)Wl + ox - 0.5f;
            float yl = ry * (float)Hl + oy - 0.5f;
            float x0f = floorf(xl), y0f = floorf(yl);
            int x0 = (int)x0f, y0 = (int)y0f;
            float wx1 = xl - x0f, wy1 = yl - y0f;
            float wx0 = 1.f - wx1, wy0 = 1.f - wy1;
            float aww = logit[l * 4 + p] * inv;

            floatx4 sv = (floatx4){0.f, 0.f, 0.f, 0.f};
            #pragma unroll
            for (int c = 0; c < 4; ++c) {
                int dx = c & 1, dy = c >> 1;
                int xi = x0 + dx, yi = y0 + dy;
                float w = (dx ? wx1 : wx0) * (dy ? wy1 : wy0);
                bool valid = (xi >= 0) & (xi < Wl) & (yi >= 0) & (yi < Hl);
                int xc = min(max(xi, 0), Wl - 1);
                int yc = min(max(yi, 0), Hl - 1);
                floatx4 gv = *(const floatx4*)(vbase + ((size_t)(yc * Wl + xc)) * (NH_ * HD_));
                float wv = valid ? w : 0.f;
                sv += gv * wv;
            }
            acc += sv * aww;
        }
    }
    *(floatx4*)(out + (size_t)tok * C_ + lane * 4) = acc;
}

// ---------------- host launch ----------------
extern "C" void kernel_launch(void* const* d_in, const int* in_sizes, int n_in,
                              void* d_out, int out_size, void* d_ws, size_t ws_size,
                              hipStream_t stream) {
    const float* tgt_text = (const float*)d_in[0];
    const float* pos      = (const float*)d_in[1];
    const float* refpts   = (const float*)d_in[2];
    const float* src      = (const float*)d_in[3];
    // d_in[4], d_in[5]: spatial shapes / level starts (static, unused)
    const float* in_proj_w  = (const float*)d_in[6];
    const float* in_proj_b  = (const float*)d_in[7];
    const float* out_proj_w = (const float*)d_in[8];
    const float* out_proj_b = (const float*)d_in[9];
    const float* ln1_g = (const float*)d_in[10];
    const float* ln1_b = (const float*)d_in[11];
    const float* samp_off_w = (const float*)d_in[12];
    const float* samp_off_b = (const float*)d_in[13];
    const float* aw_w = (const float*)d_in[14];
    const float* aw_b = (const float*)d_in[15];
    const float* vp_w = (const float*)d_in[16];
    const float* vp_b = (const float*)d_in[17];
    const float* op_w = (const float*)d_in[18];
    const float* op_b = (const float*)d_in[19];
    const float* ln2_g = (const float*)d_in[20];
    const float* ln2_b = (const float*)d_in[21];
    const float* ffn1_w = (const float*)d_in[22];
    const float* ffn1_b = (const float*)d_in[23];
    const float* ffn2_w = (const float*)d_in[24];
    const float* ffn2_b = (const float*)d_in[25];
    const float* ln3_g = (const float*)d_in[26];
    const float* ln3_b = (const float*)d_in[27];

    const long long NC = (long long)NTOK_ * C_;    // 3,840,000
    float* ws = (float*)d_ws;
    float* A    = ws;                               // [NTOK,C]   tgt (post-LN1/LN2)
    float* Bq   = ws + NC;                          // [NTOK,C]   query; later op-proj partial1
    float* Creg = ws + 2 * NC;                      // 15,360,000: qkv -> value -> ffn hidden
    float* D12  = Creg + (long long)NTOK_ * DFF_;   // [NTOK,384] offsets|aw; also partial scratch
    float* E    = D12 + (long long)NTOK_ * 384;     // [NTOK,C]   attn out / deform out / FFN2 partial1
    float* F    = E + NC;                           // [NTOK,C]   partial0 accumulators

    const int MB  = (NTOK_ + GBM - 1) / GBM;   // 118
    const int MBV = BS_ / GBM;                 // 340

    // 1. QK projection on (tgt+pos); V projection on tgt (into qkv, ldc=768)
    gemm_bias<<<dim3(MB, 4, 1), 256, 0, stream>>>(tgt_text, pos, in_proj_w, nullptr, 0,
        in_proj_b, nullptr, Creg, 0, NTOK_, 512, 256, 256, 768, 0);
    gemm_bias<<<dim3(MB, 2, 1), 256, 0, stream>>>(tgt_text, nullptr, in_proj_w + 512 * 256, nullptr, 0,
        in_proj_b + 512, nullptr, Creg + 512, 0, NTOK_, 256, 256, 256, 768, 0);
    // 2. self-attention
    attn_kernel<<<B_ * Q_ * NH_, 64, 0, stream>>>(Creg, E);
    // 3. out projection, split-K x2: partial0=F, partial1=D12 (dead until step 6)
    gemm_bias<<<dim3(MB, 2, 2), 256, 0, stream>>>(E, nullptr, out_proj_w, nullptr, 0,
        out_proj_b, nullptr, F, (long long)(D12 - F), NTOK_, 256, 256, 128, 256, 0);
    // 4. LN1 (+ residual over 2 partials), and query = tgt + pos
    ln_kernel<<<NTOK_, 256, 0, stream>>>(tgt_text, F, 2, (long long)(D12 - F),
                                         ln1_g, ln1_b, A, pos, Bq);
    // 5. value projection
    gemm_bias<<<dim3(MBV, 2, 1), 256, 0, stream>>>(src, nullptr, vp_w, nullptr, 0,
        vp_b, nullptr, Creg, 0, BS_, 256, 256, 256, 256, 0);
    // 6. sampling offsets + aw logits, merged (N=384, dual weights)
    gemm_bias<<<dim3(MB, 3, 1), 256, 0, stream>>>(Bq, nullptr, samp_off_w, aw_w, 256,
        samp_off_b, aw_b, D12, 0, NTOK_, 384, 256, 256, 384, 0);
    // 7. deformable sampling (aw softmax fused); one wave per token
    deform_kernel<<<NTOK_ / 4, 256, 0, stream>>>(Creg, D12, refpts, E);
    // 8. output projection of cross-attn, split-K x2: partial0=F, partial1=Bq (dead)
    gemm_bias<<<dim3(MB, 2, 2), 256, 0, stream>>>(E, nullptr, op_w, nullptr, 0,
        op_b, nullptr, F, (long long)(Bq - F), NTOK_, 256, 256, 128, 256, 0);
    // 9. LN2 (+ residual over 2 partials), in place on A
    ln_kernel<<<NTOK_, 256, 0, stream>>>(A, F, 2, (long long)(Bq - F),
                                         ln2_g, ln2_b, A, nullptr, nullptr);
    // 10. FFN1 + ReLU
    gemm_bias<<<dim3(MB, 8, 1), 256, 0, stream>>>(A, nullptr, ffn1_w, nullptr, 0,
        ffn1_b, nullptr, Creg, 0, NTOK_, DFF_, 256, 256, DFF_, 1);
    // 11. FFN2, split-K x2 (512 each): partial0=F, partial1=E (dead)
    gemm_bias<<<dim3(MB, 2, 2), 256, 0, stream>>>(Creg, nullptr, ffn2_w, nullptr, 0,
        ffn2_b, nullptr, F, (long long)(E - F), NTOK_, 256, 1024, 512, 256, 0);
    // 12. LN3 (+ residual over 2 partials) -> d_out
    ln_kernel<<<NTOK_, 256, 0, stream>>>(A, F, 2, (long long)(E - F),
                                         ln3_g, ln3_b, (float*)d_out, nullptr, nullptr);
}